// Round 7
// baseline (263.129 us; speedup 1.0000x reference)
//
#include <hip/hip_runtime.h>
#include <cstdint>
#include <cstddef>

#define B_N 32
#define A_N 32768
#define G_N 50
#define C_N 22
#define BA  (B_N * A_N)

#define GC 4
#define NCHUNK ((G_N + GC - 1) / GC)   // 13
#define ASEG 16                        // anchor segments
#define ASEG_LEN (A_N / ASEG)          // 2048

#define SEL_CAP 4096   // survivor list capacity (LDS); fallback to global rescan if exceeded

// ---------------- helpers ----------------

__device__ __forceinline__ float iou_one(float gx0, float gy0, float gx1, float gy1, float ga,
                                         float ax0, float ay0, float ax1, float ay1, float aa) {
    // mirror reference op order: inter / (a0 + a1 - inter + 1e-5)
    float lx = fmaxf(gx0, ax0), ly = fmaxf(gy0, ay0);
    float rx = fminf(gx1, ax1), ry = fminf(gy1, ay1);
    float iw = fmaxf(rx - lx, 0.0f), ih = fmaxf(ry - ly, 0.0f);
    float inter = iw * ih;
    return inter / (ga + aa - inter + 1e-5f);
}

__device__ __forceinline__ unsigned int f2key(float x) {
    unsigned int u = __float_as_uint(x);
    return (u & 0x80000000u) ? ~u : (u | 0x80000000u);
}

__device__ __forceinline__ float key2f(unsigned int k) {
    return __uint_as_float((k & 0x80000000u) ? (k & 0x7FFFFFFFu) : ~k);
}

// ---------------- kernels ----------------

// zero 128 header words + bp_best[B_N*G_N] u64
__global__ void init_kernel(float* hdr, unsigned long long* bp_best) {
    if (threadIdx.x < 128) hdr[threadIdx.x] = 0.0f;
    for (int i = threadIdx.x; i < B_N * G_N; i += 256) bp_best[i] = 0ull;
}

// block = (b, g-chunk of GC, anchor-segment): partial argmax over 2048 anchors
// for GC gts; combine via packed-u64 atomicMax (iou-key hi, ~a lo -> smallest a on ties)
__global__ __launch_bounds__(256) void best_prior_kernel(
        const float* __restrict__ gts, const int* __restrict__ counts,
        const float* __restrict__ anchors, unsigned long long* __restrict__ bp_best) {
    int blk = blockIdx.x;
    int b   = blk / (NCHUNK * ASEG);
    int rem = blk % (NCHUNK * ASEG);
    int ch  = rem / ASEG;
    int seg = rem % ASEG;
    int g0  = ch * GC;
    int cnt = counts[b];
    if (g0 >= cnt) return;                 // uniform exit
    // uniform (scalar) gt loads; zero-box for j >= valid count (iou=0, never stored)
    float gx0[GC], gy0[GC], gx1[GC], gy1[GC], ga[GC];
    #pragma unroll
    for (int j = 0; j < GC; ++j) {
        if (g0 + j < cnt) {
            const float* p = gts + (size_t)(b * G_N + g0 + j) * 5;
            gx0[j] = p[0]; gy0[j] = p[1]; gx1[j] = p[2]; gy1[j] = p[3];
            ga[j] = fmaxf(gx1[j] - gx0[j], 0.0f) * fmaxf(gy1[j] - gy0[j], 0.0f);
        } else { gx0[j] = 0.f; gy0[j] = 0.f; gx1[j] = 0.f; gy1[j] = 0.f; ga[j] = 0.f; }
    }
    unsigned long long best[GC];
    #pragma unroll
    for (int j = 0; j < GC; ++j) best[j] = 0ull;
    int a0 = seg * ASEG_LEN;
    for (int a = a0 + threadIdx.x; a < a0 + ASEG_LEN; a += 256) {
        float4 an = reinterpret_cast<const float4*>(anchors)[a];
        float aa = fmaxf(an.z - an.x, 0.0f) * fmaxf(an.w - an.y, 0.0f);
        #pragma unroll
        for (int j = 0; j < GC; ++j) {
            float iou = iou_one(gx0[j], gy0[j], gx1[j], gy1[j], ga[j],
                                an.x, an.y, an.z, an.w, aa);
            unsigned long long key = ((unsigned long long)f2key(iou) << 32) | (unsigned)(~a);
            if (key > best[j]) best[j] = key;
        }
    }
    // wave-level reduce (max of packed keys), then one atomic per wave per g
    #pragma unroll
    for (int j = 0; j < GC; ++j) {
        for (int o = 32; o > 0; o >>= 1) {
            unsigned long long other = __shfl_down(best[j], o, 64);
            if (other > best[j]) best[j] = other;
        }
    }
    if ((threadIdx.x & 63) == 0) {
        int ng = cnt - g0; if (ng > GC) ng = GC;
        for (int j = 0; j < ng; ++j)
            atomicMax(&bp_best[b * G_N + g0 + j], best[j]);
    }
}

// fused per-anchor pass: best-target argmax + force-match override + label +
// smooth-L1 loc loss + log-softmax (mining value + positive CE) + reductions
// conf rows for the block's 256 consecutive anchors are one contiguous 22.5KB
// chunk -> stage via coalesced float4 into LDS, read rows from LDS.
__global__ __launch_bounds__(256) void fused_kernel(
        const float* __restrict__ gts, const int* __restrict__ counts,
        const float* __restrict__ anchors, const float* __restrict__ pred_loc,
        const float* __restrict__ conf, const unsigned long long* __restrict__ bp_best,
        float* __restrict__ mining, float* __restrict__ loc_part,
        float* __restrict__ ce_part, int* __restrict__ num_pos_row) {
    int blk = blockIdx.x;
    int tid = threadIdx.x;
    int i = blk * 256 + tid;
    int b = blk >> 7;                      // 128 blocks per batch row
    int a = i & (A_N - 1);
    int cnt = counts[b];
    __shared__ float sc[256 * C_N];        // conf tile (22528 B)
    __shared__ float sg[G_N][5];           // x0,y0,x1,y1,area
    __shared__ int   sl[G_N];              // gt label
    __shared__ int   sp[G_N];              // forced prior index per g (-1 if none)

    // coalesced conf staging: 1408 float4 = 5*256 + 128
    {
        const float4* c4 = reinterpret_cast<const float4*>(conf) + (size_t)blk * (256 * C_N / 4);
        float4* s4 = reinterpret_cast<float4*>(sc);
        #pragma unroll
        for (int t = 0; t < 5; ++t) s4[tid + t * 256] = c4[tid + t * 256];
        if (tid < 128) s4[tid + 5 * 256] = c4[tid + 5 * 256];
    }
    if (tid < G_N) {
        int g = tid;
        const float* gtb = gts + (size_t)(b * G_N + g) * 5;
        float x0 = gtb[0], y0 = gtb[1], x1 = gtb[2], y1 = gtb[3];
        sg[g][0] = x0; sg[g][1] = y0; sg[g][2] = x1; sg[g][3] = y1;
        sg[g][4] = fmaxf(x1 - x0, 0.0f) * fmaxf(y1 - y0, 0.0f);
        sl[g] = (int)gtb[4];
        sp[g] = (int)(~(unsigned)(bp_best[b * G_N + g] & 0xFFFFFFFFull)); // -1 if unwritten
    }
    __syncthreads();

    float4 an = reinterpret_cast<const float4*>(anchors)[a];
    float aa = fmaxf(an.z - an.x, 0.0f) * fmaxf(an.w - an.y, 0.0f);
    float best = -2.0f; int gi = 0;
    for (int g = 0; g < cnt; ++g) {
        float iou = iou_one(sg[g][0], sg[g][1], sg[g][2], sg[g][3], sg[g][4],
                            an.x, an.y, an.z, an.w, aa);
        if (iou > best) { best = iou; gi = g; }     // first occurrence = smallest g
    }
    // force-match override (ascending g, last-wins = scatter semantics)
    bool forced = false;
    for (int g = 0; g < cnt; ++g) {
        if (sp[g] == a) { gi = g; forced = true; }
    }
    float iou_eff = forced ? 2.0f : best;
    int label = 0;
    if (!(iou_eff < 0.5f)) label = sl[gi];
    bool pos = label > 0;

    // smooth-L1 localisation loss (positives only), exact ref FP order
    float contrib = 0.0f;
    if (pos) {
        float acx = (an.x + an.z) * 0.5f, acy = (an.y + an.w) * 0.5f;
        float aw = an.z - an.x, ah = an.w - an.y;
        float gx0 = sg[gi][0], gy0 = sg[gi][1], gx1 = sg[gi][2], gy1 = sg[gi][3];
        float cx = (gx0 + gx1) * 0.5f, cy = (gy0 + gy1) * 0.5f;
        float w = gx1 - gx0, h = gy1 - gy0;
        float l0 = ((cx - acx) / aw) / 0.1f;
        float l1 = ((cy - acy) / ah) / 0.1f;
        float l2 = logf(fmaxf(w / aw, 1e-8f)) / 0.2f;
        float l3 = logf(fmaxf(h / ah, 1e-8f)) / 0.2f;
        float4 p = reinterpret_cast<const float4*>(pred_loc)[i];
        float d0 = fabsf(p.x - l0), d1 = fabsf(p.y - l1);
        float d2 = fabsf(p.z - l2), d3 = fabsf(p.w - l3);
        contrib  = (d0 < 1.0f ? 0.5f * d0 * d0 : d0 - 0.5f);
        contrib += (d1 < 1.0f ? 0.5f * d1 * d1 : d1 - 0.5f);
        contrib += (d2 < 1.0f ? 0.5f * d2 * d2 : d2 - 0.5f);
        contrib += (d3 < 1.0f ? 0.5f * d3 * d3 : d3 - 0.5f);
    }

    // log-softmax from LDS row, FP order mirrors jax.nn.log_softmax
    float v[C_N];
    {
        const float2* myrow = reinterpret_cast<const float2*>(sc + tid * C_N);
        #pragma unroll
        for (int j = 0; j < C_N / 2; ++j) { float2 t = myrow[j]; v[2 * j] = t.x; v[2 * j + 1] = t.y; }
    }
    float m = v[0];
    #pragma unroll
    for (int j = 1; j < C_N; ++j) m = fmaxf(m, v[j]);
    float s = 0.0f;
    #pragma unroll
    for (int j = 0; j < C_N; ++j) s += expf(v[j] - m);
    float ls = logf(s);
    float ce_pos = 0.0f;
    if (pos) {
        float vl = v[0];
        #pragma unroll
        for (int j = 1; j < C_N; ++j) vl = (j == label) ? v[j] : vl;  // register select
        ce_pos = ls - (vl - m);
        mining[i] = __int_as_float(0xFF800000);  // -inf
    } else {
        mining[i] = ls - (v[0] - m);             // bg_loss
    }

    // block reduction: loc sum, pos CE sum, pos count
    unsigned long long bal = __ballot(pos);
    for (int o = 32; o > 0; o >>= 1) {
        contrib += __shfl_down(contrib, o, 64);
        ce_pos  += __shfl_down(ce_pos, o, 64);
    }
    __shared__ float swl[4], swc[4];
    __shared__ int   swi[4];
    int wid = tid >> 6, lane = tid & 63;
    if (lane == 0) { swl[wid] = contrib; swc[wid] = ce_pos; swi[wid] = __popcll(bal); }
    __syncthreads();
    if (tid == 0) {
        float sL = swl[0] + swl[1] + swl[2] + swl[3];
        float sC = swc[0] + swc[1] + swc[2] + swc[3];
        int   c  = swi[0] + swi[1] + swi[2] + swi[3];
        int slot = blk & 31;
        if (sL != 0.0f) atomicAdd(&loc_part[slot], sL);
        if (sC != 0.0f) atomicAdd(&ce_part[slot], sC);
        if (c) atomicAdd(&num_pos_row[b], c);
    }
}

// ---- radix select support: suffix-scan over packed-u16 histogram, pick bin + rank ----
__device__ __forceinline__ void scan_pick(unsigned* hist, int nwords,
                                          unsigned* sA, unsigned* sB,
                                          int krem, int* s_bin, int* s_krem) {
    int t = threadIdx.x;
    unsigned lo = 0, hi = 0;
    if (t < nwords) { unsigned w = hist[t]; lo = w & 0xFFFFu; hi = w >> 16; }
    sA[t] = lo + hi;
    __syncthreads();
    unsigned* src = sA; unsigned* dst = sB;
    for (int d = 1; d < 1024; d <<= 1) {
        unsigned vv = src[t] + ((t + d < 1024) ? src[t + d] : 0u);
        dst[t] = vv;
        __syncthreads();
        unsigned* tmp = src; src = dst; dst = tmp;
    }
    unsigned incl = src[t];
    unsigned incl_next = (t < 1023) ? src[t + 1] : 0u;
    unsigned uk = (unsigned)krem;
    if (incl >= uk && incl_next < uk) {     // unique crossing thread
        unsigned cum = incl_next;
        if (cum + hi >= uk) { *s_bin = 2 * t + 1; *s_krem = (int)(uk - cum); }
        else                { *s_bin = 2 * t;     *s_krem = (int)(uk - cum - hi); }
    }
    __syncthreads();
}

// per-row 3-level (11/11/10 bit) histogram select: sum of top-k bg_loss, k = 3*num_pos
__global__ __launch_bounds__(1024) void select_kernel(
        const float* __restrict__ mining, const int* __restrict__ num_pos_row,
        float* __restrict__ neg_sum) {
    int b = blockIdx.x;
    int tid = threadIdx.x;
    int np = num_pos_row[b];
    long long k = 3LL * np;
    int num_neg = A_N - np;
    int k_eff = (int)((k < (long long)num_neg) ? k : (long long)num_neg);
    if (k_eff <= 0) { if (tid == 0) neg_sum[b] = 0.0f; return; }   // uniform exit
    const float4* row4 = reinterpret_cast<const float4*>(mining + (size_t)b * A_N);

    __shared__ unsigned hist[1024];     // 2048 u16 bins packed
    __shared__ unsigned sA[1024], sB[1024];
    __shared__ unsigned surv[SEL_CAP];
    __shared__ int s_n1, s_bin, s_krem;
    __shared__ float swf[16];

    // ---- level 1: bits [31:21] (2048 bins) ----
    hist[tid] = 0;
    if (tid == 0) s_n1 = 0;
    __syncthreads();
    #pragma unroll
    for (int it = 0; it < A_N / 4 / 1024; ++it) {
        float4 vv = row4[tid + it * 1024];
        unsigned k0 = f2key(vv.x), k1 = f2key(vv.y), k2 = f2key(vv.z), k3 = f2key(vv.w);
        unsigned b0 = k0 >> 21, b1 = k1 >> 21, b2 = k2 >> 21, b3 = k3 >> 21;
        atomicAdd(&hist[b0 >> 1], (b0 & 1) ? 65536u : 1u);
        atomicAdd(&hist[b1 >> 1], (b1 & 1) ? 65536u : 1u);
        atomicAdd(&hist[b2 >> 1], (b2 & 1) ? 65536u : 1u);
        atomicAdd(&hist[b3 >> 1], (b3 & 1) ? 65536u : 1u);
    }
    __syncthreads();
    scan_pick(hist, 1024, sA, sB, k_eff, &s_bin, &s_krem);
    unsigned bin1 = (unsigned)s_bin;
    int krem1 = s_krem;
    __syncthreads();

    // ---- pass 2: sum strictly-above bins + collect survivors of bin1 ----
    float sum_sel = 0.0f;
    #pragma unroll
    for (int it = 0; it < A_N / 4 / 1024; ++it) {
        float4 vv = row4[tid + it * 1024];
        float xs[4] = {vv.x, vv.y, vv.z, vv.w};
        #pragma unroll
        for (int e = 0; e < 4; ++e) {
            unsigned key = f2key(xs[e]);
            unsigned t11 = key >> 21;
            if (t11 > bin1) sum_sel += xs[e];
            else if (t11 == bin1) {
                int p = atomicAdd(&s_n1, 1);
                if (p < SEL_CAP) surv[p] = key;
            }
        }
    }
    __syncthreads();
    int n1 = s_n1;
    bool in_lds = (n1 <= SEL_CAP);

    // ---- level 2: bits [20:10] among survivors ----
    hist[tid] = 0;
    __syncthreads();
    if (in_lds) {
        for (int ii = tid; ii < n1; ii += 1024) {
            unsigned bin = (surv[ii] >> 10) & 0x7FFu;
            atomicAdd(&hist[bin >> 1], (bin & 1) ? 65536u : 1u);
        }
    } else {
        for (int it = 0; it < A_N / 4 / 1024; ++it) {
            float4 vv = row4[tid + it * 1024];
            float xs[4] = {vv.x, vv.y, vv.z, vv.w};
            for (int e = 0; e < 4; ++e) {
                unsigned key = f2key(xs[e]);
                if ((key >> 21) == bin1) {
                    unsigned bin = (key >> 10) & 0x7FFu;
                    atomicAdd(&hist[bin >> 1], (bin & 1) ? 65536u : 1u);
                }
            }
        }
    }
    __syncthreads();
    scan_pick(hist, 1024, sA, sB, krem1, &s_bin, &s_krem);
    unsigned prefix22 = (bin1 << 11) | (unsigned)s_bin;
    int krem2 = s_krem;
    __syncthreads();

    // ---- level 3: bits [9:0] ----
    hist[tid] = 0;
    __syncthreads();
    if (in_lds) {
        for (int ii = tid; ii < n1; ii += 1024) {
            unsigned key = surv[ii];
            if ((key >> 10) == prefix22) {
                unsigned bin = key & 0x3FFu;
                atomicAdd(&hist[bin >> 1], (bin & 1) ? 65536u : 1u);
            }
        }
    } else {
        for (int it = 0; it < A_N / 4 / 1024; ++it) {
            float4 vv = row4[tid + it * 1024];
            float xs[4] = {vv.x, vv.y, vv.z, vv.w};
            for (int e = 0; e < 4; ++e) {
                unsigned key = f2key(xs[e]);
                if ((key >> 10) == prefix22) {
                    unsigned bin = key & 0x3FFu;
                    atomicAdd(&hist[bin >> 1], (bin & 1) ? 65536u : 1u);
                }
            }
        }
    }
    __syncthreads();
    scan_pick(hist, 512, sA, sB, krem2, &s_bin, &s_krem);
    unsigned kth = (prefix22 << 10) | (unsigned)s_bin;
    int krem3 = s_krem;
    __syncthreads();

    // ---- final: add survivors strictly above kth ----
    if (in_lds) {
        for (int ii = tid; ii < n1; ii += 1024) {
            unsigned key = surv[ii];
            if (key > kth) sum_sel += key2f(key);
        }
    } else {
        for (int it = 0; it < A_N / 4 / 1024; ++it) {
            float4 vv = row4[tid + it * 1024];
            float xs[4] = {vv.x, vv.y, vv.z, vv.w};
            for (int e = 0; e < 4; ++e) {
                unsigned key = f2key(xs[e]);
                if ((key >> 21) == bin1 && key > kth) sum_sel += xs[e];
            }
        }
    }
    for (int o = 32; o > 0; o >>= 1) sum_sel += __shfl_down(sum_sel, o, 64);
    int wid = tid >> 6, lane = tid & 63;
    if (lane == 0) swf[wid] = sum_sel;
    __syncthreads();
    if (tid == 0) {
        float tot = 0.0f;
        #pragma unroll
        for (int w = 0; w < 16; ++w) tot += swf[w];
        neg_sum[b] = tot + (float)krem3 * key2f(kth);   // ties share the identical value
    }
}

__global__ void final_kernel(const float* __restrict__ loc_part, const float* __restrict__ ce_part,
                             const int* __restrict__ num_pos_row, const float* __restrict__ neg_sum,
                             float* __restrict__ out) {
    if (threadIdx.x != 0) return;
    int tot = 0;
    for (int b = 0; b < B_N; ++b) tot += num_pos_row[b];
    float npos = fmaxf(1.0f, (float)tot);
    float L = 0.0f, Cp = 0.0f, Ng = 0.0f;
    for (int j = 0; j < B_N; ++j) { L += loc_part[j]; Cp += ce_part[j]; Ng += neg_sum[j]; }
    out[0] = L / (npos * 4.0f);          // localisation loss
    out[1] = (Cp + Ng) / (npos * 4.0f);  // classification loss
}

// ---------------- launch ----------------

extern "C" void kernel_launch(void* const* d_in, const int* in_sizes, int n_in,
                              void* d_out, int out_size, void* d_ws, size_t ws_size,
                              hipStream_t stream) {
    const float* conf     = (const float*)d_in[0];
    const float* pred_loc = (const float*)d_in[1];
    const float* gts      = (const float*)d_in[2];
    const int*   counts   = (const int*)d_in[3];
    const float* anchors  = (const float*)d_in[4];
    float* out = (float*)d_out;

    char* ws = (char*)d_ws;
    float* loc_part     = (float*)ws;                 // [0:32)
    float* ce_part      = (float*)(ws + 128);         // [32:64)
    int*   num_pos_row  = (int*)(ws + 256);           // [64:96)
    float* neg_sum      = (float*)(ws + 384);         // [96:128)
    unsigned long long* bp_best = (unsigned long long*)(ws + 512);  // B*G u64 (12.8KB)
    float* mining       = (float*)(ws + 16384);       // BA floats (4MB)

    init_kernel<<<1, 256, 0, stream>>>(loc_part, bp_best);
    best_prior_kernel<<<B_N * NCHUNK * ASEG, 256, 0, stream>>>(gts, counts, anchors, bp_best);
    fused_kernel<<<BA / 256, 256, 0, stream>>>(gts, counts, anchors, pred_loc, conf, bp_best,
                                               mining, loc_part, ce_part, num_pos_row);
    select_kernel<<<B_N, 1024, 0, stream>>>(mining, num_pos_row, neg_sum);
    final_kernel<<<1, 64, 0, stream>>>(loc_part, ce_part, num_pos_row, neg_sum, out);
}

// Round 8
// 261.484 us; speedup vs baseline: 1.0063x; 1.0063x over previous
//
#include <hip/hip_runtime.h>
#include <cstdint>
#include <cstddef>

#define B_N 32
#define A_N 32768
#define G_N 50
#define C_N 22
#define BA  (B_N * A_N)

#define GC 4
#define NCHUNK ((G_N + GC - 1) / GC)   // 13
#define ASEG 16                        // anchor segments
#define ASEG_LEN (A_N / ASEG)          // 2048

#define SEL_CAP 4096   // survivor list capacity (LDS); fallback to global rescan if exceeded

// ---------------- helpers ----------------

__device__ __forceinline__ float iou_one(float gx0, float gy0, float gx1, float gy1, float ga,
                                         float ax0, float ay0, float ax1, float ay1, float aa) {
    // mirror reference op order: inter / (a0 + a1 - inter + 1e-5)
    float lx = fmaxf(gx0, ax0), ly = fmaxf(gy0, ay0);
    float rx = fminf(gx1, ax1), ry = fminf(gy1, ay1);
    float iw = fmaxf(rx - lx, 0.0f), ih = fmaxf(ry - ly, 0.0f);
    float inter = iw * ih;
    return inter / (ga + aa - inter + 1e-5f);
}

__device__ __forceinline__ unsigned int f2key(float x) {
    unsigned int u = __float_as_uint(x);
    return (u & 0x80000000u) ? ~u : (u | 0x80000000u);
}

__device__ __forceinline__ float key2f(unsigned int k) {
    return __uint_as_float((k & 0x80000000u) ? (k & 0x7FFFFFFFu) : ~k);
}

// ---------------- kernels ----------------

// zero 128 header words + bp_best[B_N*G_N] u64
__global__ void init_kernel(float* hdr, unsigned long long* bp_best) {
    if (threadIdx.x < 128) hdr[threadIdx.x] = 0.0f;
    for (int i = threadIdx.x; i < B_N * G_N; i += 256) bp_best[i] = 0ull;
}

// block = (b, g-chunk of GC, anchor-segment): partial argmax over 2048 anchors
// for GC gts; combine via packed-u64 atomicMax (iou-key hi, ~a lo -> smallest a on ties)
__global__ __launch_bounds__(256) void best_prior_kernel(
        const float* __restrict__ gts, const int* __restrict__ counts,
        const float* __restrict__ anchors, unsigned long long* __restrict__ bp_best) {
    int blk = blockIdx.x;
    int b   = blk / (NCHUNK * ASEG);
    int rem = blk % (NCHUNK * ASEG);
    int ch  = rem / ASEG;
    int seg = rem % ASEG;
    int g0  = ch * GC;
    int cnt = counts[b];
    if (g0 >= cnt) return;                 // uniform exit
    // uniform (scalar) gt loads; zero-box for j >= valid count (iou=0, never stored)
    float gx0[GC], gy0[GC], gx1[GC], gy1[GC], ga[GC];
    #pragma unroll
    for (int j = 0; j < GC; ++j) {
        if (g0 + j < cnt) {
            const float* p = gts + (size_t)(b * G_N + g0 + j) * 5;
            gx0[j] = p[0]; gy0[j] = p[1]; gx1[j] = p[2]; gy1[j] = p[3];
            ga[j] = fmaxf(gx1[j] - gx0[j], 0.0f) * fmaxf(gy1[j] - gy0[j], 0.0f);
        } else { gx0[j] = 0.f; gy0[j] = 0.f; gx1[j] = 0.f; gy1[j] = 0.f; ga[j] = 0.f; }
    }
    unsigned long long best[GC];
    #pragma unroll
    for (int j = 0; j < GC; ++j) best[j] = 0ull;
    int a0 = seg * ASEG_LEN;
    for (int a = a0 + threadIdx.x; a < a0 + ASEG_LEN; a += 256) {
        float4 an = reinterpret_cast<const float4*>(anchors)[a];
        float aa = fmaxf(an.z - an.x, 0.0f) * fmaxf(an.w - an.y, 0.0f);
        #pragma unroll
        for (int j = 0; j < GC; ++j) {
            float iou = iou_one(gx0[j], gy0[j], gx1[j], gy1[j], ga[j],
                                an.x, an.y, an.z, an.w, aa);
            unsigned long long key = ((unsigned long long)f2key(iou) << 32) | (unsigned)(~a);
            if (key > best[j]) best[j] = key;
        }
    }
    // wave-level reduce (max of packed keys), then one atomic per wave per g
    #pragma unroll
    for (int j = 0; j < GC; ++j) {
        for (int o = 32; o > 0; o >>= 1) {
            unsigned long long other = __shfl_down(best[j], o, 64);
            if (other > best[j]) best[j] = other;
        }
    }
    if ((threadIdx.x & 63) == 0) {
        int ng = cnt - g0; if (ng > GC) ng = GC;
        for (int j = 0; j < ng; ++j)
            atomicMax(&bp_best[b * G_N + g0 + j], best[j]);
    }
}

// softmax + mining write + pos-CE accumulate for one anchor row (global conf reads)
// FP order mirrors jax.nn.log_softmax
__device__ __forceinline__ void softmax_one(const float* __restrict__ conf, size_t i,
                                            int lab, bool pos,
                                            float* __restrict__ mining, float& ce_acc) {
    float v[C_N];
    const float2* c2 = reinterpret_cast<const float2*>(conf + i * C_N);
    #pragma unroll
    for (int j = 0; j < C_N / 2; ++j) { float2 t = c2[j]; v[2 * j] = t.x; v[2 * j + 1] = t.y; }
    float m = v[0];
    #pragma unroll
    for (int j = 1; j < C_N; ++j) m = fmaxf(m, v[j]);
    float s = 0.0f;
    #pragma unroll
    for (int j = 0; j < C_N; ++j) s += expf(v[j] - m);
    float ls = logf(s);
    if (pos) {
        float vl = v[0];
        #pragma unroll
        for (int j = 1; j < C_N; ++j) vl = (j == lab) ? v[j] : vl;  // register select
        ce_acc += ls - (vl - m);
        mining[i] = __int_as_float(0xFF800000);  // -inf
    } else {
        mining[i] = ls - (v[0] - m);             // bg_loss
    }
}

// smooth-L1 localisation term for one positive anchor, exact ref FP order
__device__ __forceinline__ float loc_term(float4 an, const float sgrow[5],
                                          const float* __restrict__ pred_loc, size_t i) {
    float acx = (an.x + an.z) * 0.5f, acy = (an.y + an.w) * 0.5f;
    float aw = an.z - an.x, ah = an.w - an.y;
    float gx0 = sgrow[0], gy0 = sgrow[1], gx1 = sgrow[2], gy1 = sgrow[3];
    float cx = (gx0 + gx1) * 0.5f, cy = (gy0 + gy1) * 0.5f;
    float w = gx1 - gx0, h = gy1 - gy0;
    float l0 = ((cx - acx) / aw) / 0.1f;
    float l1 = ((cy - acy) / ah) / 0.1f;
    float l2 = logf(fmaxf(w / aw, 1e-8f)) / 0.2f;
    float l3 = logf(fmaxf(h / ah, 1e-8f)) / 0.2f;
    float4 p = reinterpret_cast<const float4*>(pred_loc)[i];
    float d0 = fabsf(p.x - l0), d1 = fabsf(p.y - l1);
    float d2 = fabsf(p.z - l2), d3 = fabsf(p.w - l3);
    float c;
    c  = (d0 < 1.0f ? 0.5f * d0 * d0 : d0 - 0.5f);
    c += (d1 < 1.0f ? 0.5f * d1 * d1 : d1 - 0.5f);
    c += (d2 < 1.0f ? 0.5f * d2 * d2 : d2 - 0.5f);
    c += (d3 < 1.0f ? 0.5f * d3 * d3 : d3 - 0.5f);
    return c;
}

// fused per-anchor pass, TWO anchors per thread (stride-256 pairing within a
// 512-anchor block): best-target argmax + force-match override + label +
// smooth-L1 loc loss + log-softmax (mining + positive CE) + reductions.
// blk_off splits the grid into 4 dispatches for profiling visibility.
__global__ __launch_bounds__(256) void fused_kernel(
        const float* __restrict__ gts, const int* __restrict__ counts,
        const float* __restrict__ anchors, const float* __restrict__ pred_loc,
        const float* __restrict__ conf, const unsigned long long* __restrict__ bp_best,
        float* __restrict__ mining, float* __restrict__ loc_part,
        float* __restrict__ ce_part, int* __restrict__ num_pos_row, int blk_off) {
    int blk = blockIdx.x + blk_off;
    int tid = threadIdx.x;
    int b = blk >> 6;                      // 64 blocks per batch row (512 anchors each)
    int abase = (blk & 63) << 9;           // *512
    int a0 = abase + tid, a1 = a0 + 256;
    size_t i0 = (size_t)b * A_N + a0, i1 = i0 + 256;
    int cnt = counts[b];
    __shared__ float sg[G_N][5];           // x0,y0,x1,y1,area
    __shared__ int   sl[G_N];              // gt label
    __shared__ int   sp[G_N];              // forced prior index per g (-1 if none)
    if (tid < G_N) {
        int g = tid;
        const float* gtb = gts + (size_t)(b * G_N + g) * 5;
        float x0 = gtb[0], y0 = gtb[1], x1 = gtb[2], y1 = gtb[3];
        sg[g][0] = x0; sg[g][1] = y0; sg[g][2] = x1; sg[g][3] = y1;
        sg[g][4] = fmaxf(x1 - x0, 0.0f) * fmaxf(y1 - y0, 0.0f);
        sl[g] = (int)gtb[4];
        sp[g] = (int)(~(unsigned)(bp_best[b * G_N + g] & 0xFFFFFFFFull)); // -1 if unwritten
    }
    __syncthreads();

    float4 an0 = reinterpret_cast<const float4*>(anchors)[a0];
    float4 an1 = reinterpret_cast<const float4*>(anchors)[a1];
    float aa0 = fmaxf(an0.z - an0.x, 0.0f) * fmaxf(an0.w - an0.y, 0.0f);
    float aa1 = fmaxf(an1.z - an1.x, 0.0f) * fmaxf(an1.w - an1.y, 0.0f);
    float best0 = -2.0f, best1 = -2.0f;
    int gi0 = 0, gi1 = 0;
    for (int g = 0; g < cnt; ++g) {
        float x0 = sg[g][0], y0 = sg[g][1], x1 = sg[g][2], y1 = sg[g][3], ar = sg[g][4];
        float iou0 = iou_one(x0, y0, x1, y1, ar, an0.x, an0.y, an0.z, an0.w, aa0);
        float iou1 = iou_one(x0, y0, x1, y1, ar, an1.x, an1.y, an1.z, an1.w, aa1);
        if (iou0 > best0) { best0 = iou0; gi0 = g; }   // first occurrence = smallest g
        if (iou1 > best1) { best1 = iou1; gi1 = g; }
    }
    // force-match override (ascending g, last-wins = scatter semantics)
    bool f0 = false, f1 = false;
    for (int g = 0; g < cnt; ++g) {
        int p = sp[g];
        if (p == a0) { gi0 = g; f0 = true; }
        if (p == a1) { gi1 = g; f1 = true; }
    }
    float ie0 = f0 ? 2.0f : best0;
    float ie1 = f1 ? 2.0f : best1;
    int lab0 = 0; if (!(ie0 < 0.5f)) lab0 = sl[gi0];
    int lab1 = 0; if (!(ie1 < 0.5f)) lab1 = sl[gi1];
    bool pos0 = lab0 > 0, pos1 = lab1 > 0;

    float contrib = 0.0f;
    if (pos0) contrib += loc_term(an0, sg[gi0], pred_loc, i0);
    if (pos1) contrib += loc_term(an1, sg[gi1], pred_loc, i1);

    float ce = 0.0f;
    softmax_one(conf, i0, lab0, pos0, mining, ce);
    softmax_one(conf, i1, lab1, pos1, mining, ce);

    // block reduction: loc sum, pos CE sum, pos count
    unsigned long long bal0 = __ballot(pos0);
    unsigned long long bal1 = __ballot(pos1);
    for (int o = 32; o > 0; o >>= 1) {
        contrib += __shfl_down(contrib, o, 64);
        ce      += __shfl_down(ce, o, 64);
    }
    __shared__ float swl[4], swc[4];
    __shared__ int   swi[4];
    int wid = tid >> 6, lane = tid & 63;
    if (lane == 0) { swl[wid] = contrib; swc[wid] = ce; swi[wid] = __popcll(bal0) + __popcll(bal1); }
    __syncthreads();
    if (tid == 0) {
        float sL = swl[0] + swl[1] + swl[2] + swl[3];
        float sC = swc[0] + swc[1] + swc[2] + swc[3];
        int   c  = swi[0] + swi[1] + swi[2] + swi[3];
        int slot = blk & 31;
        if (sL != 0.0f) atomicAdd(&loc_part[slot], sL);
        if (sC != 0.0f) atomicAdd(&ce_part[slot], sC);
        if (c) atomicAdd(&num_pos_row[b], c);
    }
}

// ---- radix select support: suffix-scan over packed-u16 histogram, pick bin + rank ----
__device__ __forceinline__ void scan_pick(unsigned* hist, int nwords,
                                          unsigned* sA, unsigned* sB,
                                          int krem, int* s_bin, int* s_krem) {
    int t = threadIdx.x;
    unsigned lo = 0, hi = 0;
    if (t < nwords) { unsigned w = hist[t]; lo = w & 0xFFFFu; hi = w >> 16; }
    sA[t] = lo + hi;
    __syncthreads();
    unsigned* src = sA; unsigned* dst = sB;
    for (int d = 1; d < 1024; d <<= 1) {
        unsigned vv = src[t] + ((t + d < 1024) ? src[t + d] : 0u);
        dst[t] = vv;
        __syncthreads();
        unsigned* tmp = src; src = dst; dst = tmp;
    }
    unsigned incl = src[t];
    unsigned incl_next = (t < 1023) ? src[t + 1] : 0u;
    unsigned uk = (unsigned)krem;
    if (incl >= uk && incl_next < uk) {     // unique crossing thread
        unsigned cum = incl_next;
        if (cum + hi >= uk) { *s_bin = 2 * t + 1; *s_krem = (int)(uk - cum); }
        else                { *s_bin = 2 * t;     *s_krem = (int)(uk - cum - hi); }
    }
    __syncthreads();
}

// per-row 3-level (11/11/10 bit) histogram select: sum of top-k bg_loss, k = 3*num_pos
__global__ __launch_bounds__(1024) void select_kernel(
        const float* __restrict__ mining, const int* __restrict__ num_pos_row,
        float* __restrict__ neg_sum) {
    int b = blockIdx.x;
    int tid = threadIdx.x;
    int np = num_pos_row[b];
    long long k = 3LL * np;
    int num_neg = A_N - np;
    int k_eff = (int)((k < (long long)num_neg) ? k : (long long)num_neg);
    if (k_eff <= 0) { if (tid == 0) neg_sum[b] = 0.0f; return; }   // uniform exit
    const float4* row4 = reinterpret_cast<const float4*>(mining + (size_t)b * A_N);

    __shared__ unsigned hist[1024];     // 2048 u16 bins packed
    __shared__ unsigned sA[1024], sB[1024];
    __shared__ unsigned surv[SEL_CAP];
    __shared__ int s_n1, s_bin, s_krem;
    __shared__ float swf[16];

    // ---- level 1: bits [31:21] (2048 bins) ----
    hist[tid] = 0;
    if (tid == 0) s_n1 = 0;
    __syncthreads();
    #pragma unroll
    for (int it = 0; it < A_N / 4 / 1024; ++it) {
        float4 vv = row4[tid + it * 1024];
        unsigned k0 = f2key(vv.x), k1 = f2key(vv.y), k2 = f2key(vv.z), k3 = f2key(vv.w);
        unsigned b0 = k0 >> 21, b1 = k1 >> 21, b2 = k2 >> 21, b3 = k3 >> 21;
        atomicAdd(&hist[b0 >> 1], (b0 & 1) ? 65536u : 1u);
        atomicAdd(&hist[b1 >> 1], (b1 & 1) ? 65536u : 1u);
        atomicAdd(&hist[b2 >> 1], (b2 & 1) ? 65536u : 1u);
        atomicAdd(&hist[b3 >> 1], (b3 & 1) ? 65536u : 1u);
    }
    __syncthreads();
    scan_pick(hist, 1024, sA, sB, k_eff, &s_bin, &s_krem);
    unsigned bin1 = (unsigned)s_bin;
    int krem1 = s_krem;
    __syncthreads();

    // ---- pass 2: sum strictly-above bins + collect survivors of bin1 ----
    float sum_sel = 0.0f;
    #pragma unroll
    for (int it = 0; it < A_N / 4 / 1024; ++it) {
        float4 vv = row4[tid + it * 1024];
        float xs[4] = {vv.x, vv.y, vv.z, vv.w};
        #pragma unroll
        for (int e = 0; e < 4; ++e) {
            unsigned key = f2key(xs[e]);
            unsigned t11 = key >> 21;
            if (t11 > bin1) sum_sel += xs[e];
            else if (t11 == bin1) {
                int p = atomicAdd(&s_n1, 1);
                if (p < SEL_CAP) surv[p] = key;
            }
        }
    }
    __syncthreads();
    int n1 = s_n1;
    bool in_lds = (n1 <= SEL_CAP);

    // ---- level 2: bits [20:10] among survivors ----
    hist[tid] = 0;
    __syncthreads();
    if (in_lds) {
        for (int ii = tid; ii < n1; ii += 1024) {
            unsigned bin = (surv[ii] >> 10) & 0x7FFu;
            atomicAdd(&hist[bin >> 1], (bin & 1) ? 65536u : 1u);
        }
    } else {
        for (int it = 0; it < A_N / 4 / 1024; ++it) {
            float4 vv = row4[tid + it * 1024];
            float xs[4] = {vv.x, vv.y, vv.z, vv.w};
            for (int e = 0; e < 4; ++e) {
                unsigned key = f2key(xs[e]);
                if ((key >> 21) == bin1) {
                    unsigned bin = (key >> 10) & 0x7FFu;
                    atomicAdd(&hist[bin >> 1], (bin & 1) ? 65536u : 1u);
                }
            }
        }
    }
    __syncthreads();
    scan_pick(hist, 1024, sA, sB, krem1, &s_bin, &s_krem);
    unsigned prefix22 = (bin1 << 11) | (unsigned)s_bin;
    int krem2 = s_krem;
    __syncthreads();

    // ---- level 3: bits [9:0] ----
    hist[tid] = 0;
    __syncthreads();
    if (in_lds) {
        for (int ii = tid; ii < n1; ii += 1024) {
            unsigned key = surv[ii];
            if ((key >> 10) == prefix22) {
                unsigned bin = key & 0x3FFu;
                atomicAdd(&hist[bin >> 1], (bin & 1) ? 65536u : 1u);
            }
        }
    } else {
        for (int it = 0; it < A_N / 4 / 1024; ++it) {
            float4 vv = row4[tid + it * 1024];
            float xs[4] = {vv.x, vv.y, vv.z, vv.w};
            for (int e = 0; e < 4; ++e) {
                unsigned key = f2key(xs[e]);
                if ((key >> 10) == prefix22) {
                    unsigned bin = key & 0x3FFu;
                    atomicAdd(&hist[bin >> 1], (bin & 1) ? 65536u : 1u);
                }
            }
        }
    }
    __syncthreads();
    scan_pick(hist, 512, sA, sB, krem2, &s_bin, &s_krem);
    unsigned kth = (prefix22 << 10) | (unsigned)s_bin;
    int krem3 = s_krem;
    __syncthreads();

    // ---- final: add survivors strictly above kth ----
    if (in_lds) {
        for (int ii = tid; ii < n1; ii += 1024) {
            unsigned key = surv[ii];
            if (key > kth) sum_sel += key2f(key);
        }
    } else {
        for (int it = 0; it < A_N / 4 / 1024; ++it) {
            float4 vv = row4[tid + it * 1024];
            float xs[4] = {vv.x, vv.y, vv.z, vv.w};
            for (int e = 0; e < 4; ++e) {
                unsigned key = f2key(xs[e]);
                if ((key >> 21) == bin1 && key > kth) sum_sel += xs[e];
            }
        }
    }
    for (int o = 32; o > 0; o >>= 1) sum_sel += __shfl_down(sum_sel, o, 64);
    int wid = tid >> 6, lane = tid & 63;
    if (lane == 0) swf[wid] = sum_sel;
    __syncthreads();
    if (tid == 0) {
        float tot = 0.0f;
        #pragma unroll
        for (int w = 0; w < 16; ++w) tot += swf[w];
        neg_sum[b] = tot + (float)krem3 * key2f(kth);   // ties share the identical value
    }
}

__global__ void final_kernel(const float* __restrict__ loc_part, const float* __restrict__ ce_part,
                             const int* __restrict__ num_pos_row, const float* __restrict__ neg_sum,
                             float* __restrict__ out) {
    if (threadIdx.x != 0) return;
    int tot = 0;
    for (int b = 0; b < B_N; ++b) tot += num_pos_row[b];
    float npos = fmaxf(1.0f, (float)tot);
    float L = 0.0f, Cp = 0.0f, Ng = 0.0f;
    for (int j = 0; j < B_N; ++j) { L += loc_part[j]; Cp += ce_part[j]; Ng += neg_sum[j]; }
    out[0] = L / (npos * 4.0f);          // localisation loss
    out[1] = (Cp + Ng) / (npos * 4.0f);  // classification loss
}

// ---------------- launch ----------------

extern "C" void kernel_launch(void* const* d_in, const int* in_sizes, int n_in,
                              void* d_out, int out_size, void* d_ws, size_t ws_size,
                              hipStream_t stream) {
    const float* conf     = (const float*)d_in[0];
    const float* pred_loc = (const float*)d_in[1];
    const float* gts      = (const float*)d_in[2];
    const int*   counts   = (const int*)d_in[3];
    const float* anchors  = (const float*)d_in[4];
    float* out = (float*)d_out;

    char* ws = (char*)d_ws;
    float* loc_part     = (float*)ws;                 // [0:32)
    float* ce_part      = (float*)(ws + 128);         // [32:64)
    int*   num_pos_row  = (int*)(ws + 256);           // [64:96)
    float* neg_sum      = (float*)(ws + 384);         // [96:128)
    unsigned long long* bp_best = (unsigned long long*)(ws + 512);  // B*G u64 (12.8KB)
    float* mining       = (float*)(ws + 16384);       // BA floats (4MB)

    init_kernel<<<1, 256, 0, stream>>>(loc_part, bp_best);
    best_prior_kernel<<<B_N * NCHUNK * ASEG, 256, 0, stream>>>(gts, counts, anchors, bp_best);
    // fused: 2048 blocks total (2 anchors/thread), split 4x for profiling visibility
    for (int p = 0; p < 4; ++p) {
        fused_kernel<<<512, 256, 0, stream>>>(gts, counts, anchors, pred_loc, conf, bp_best,
                                              mining, loc_part, ce_part, num_pos_row, p * 512);
    }
    select_kernel<<<B_N, 1024, 0, stream>>>(mining, num_pos_row, neg_sum);
    final_kernel<<<1, 64, 0, stream>>>(loc_part, ce_part, num_pos_row, neg_sum, out);
}